// Round 5
// baseline (481.730 us; speedup 1.0000x reference)
//
#include <hip/hip_runtime.h>
#include <stdint.h>

typedef unsigned short u16;
typedef __attribute__((ext_vector_type(8))) short short8;
typedef __attribute__((ext_vector_type(4))) float floatx4;

#define BB 16
#define NN1 1024
#define NN2 4096
#define DIM 512
#define M1 (BB*NN1)    // 16384
#define M2 (BB*NN2)    // 65536

__device__ __forceinline__ float bf2f(u16 u){
  union { unsigned int i; float f; } v; v.i = ((unsigned int)u) << 16; return v.f;
}
__device__ __forceinline__ u16 f2bf(float f){
  union { float f; unsigned int i; } v; v.f = f;
  unsigned int i = v.i;
  return (u16)((i + 0x7FFFu + ((i >> 16) & 1u)) >> 16);  // RNE (exact for bf16-quantized)
}

// packed f32x2 -> bf16x2 (RNE, single VALU instr)
__device__ __forceinline__ uint32_t cvtpk(float lo, float hi){
  uint32_t r;
  asm("v_cvt_pk_bf16_f32 %0, %1, %2" : "=v"(r) : "v"(lo), "v"(hi));
  return r;
}

// fast f32 reciprocal (1 ulp) — weights only, not orderings
__device__ __forceinline__ float rcpf(float x){
  float r; asm("v_rcp_f32 %0, %1" : "=v"(r) : "v"(x)); return r;
}

// async global->LDS, 16B per lane; LDS dest = wave-uniform base + lane*16
__device__ __forceinline__ void gload_lds16(const void* g, void* l){
  __builtin_amdgcn_global_load_lds(
      (const __attribute__((address_space(1))) void*)g,
      (__attribute__((address_space(3))) void*)l, 16, 0, 0);
}

// ---- prep: zero stats + both weight transposes (f32 [K][N] -> bf16 [N][K]) ----
__global__ void prep(const float* __restrict__ fc1_w, const float* __restrict__ fc2_w,
                     u16* __restrict__ wT1, u16* __restrict__ wT2,
                     float* __restrict__ stats){
  int idx = blockIdx.x * 256 + threadIdx.x;   // grid 3072 -> 786432
  if (idx < 2048) stats[idx] = 0.0f;
  if (idx < 512 * 1024){
    int n = idx >> 10, k = idx & 1023;        // wT1[n][k] = fc1_w[k][n]
    wT1[idx] = f2bf(fc1_w[k * 512 + n]);
  } else {
    int j = idx - 512 * 1024;
    int n = j >> 9, k = j & 511;              // wT2[n][k] = fc2_w[k][n]
    wT2[j] = f2bf(fc2_w[k * 512 + n]);
  }
}

// ---- MFMA GEMM: Y[M][512] = A_f32[M][K] @ W; BT = bf16 W^T [512][K] ----
// 512 threads / 8 waves, wave tile 64x32 -> acc[4][2] = 32 AGPR.
// Total regs <= 128-bucket (m69: HW alloc steps 64/128/256) -> 4 waves/SIMD,
// 2x the occupancy of the 144-reg 4x4 version (the stuck-27% limiter).
// 2-phase dbuf; A: f32->cvt_pk->swizzled ds_write; B: gld_lds pre-swizzled src.
__global__ __launch_bounds__(512, 4) void gemm_mfma(
    const float* __restrict__ A, const u16* __restrict__ BT,
    const float* __restrict__ bias, void* __restrict__ Yv,
    int M, int K, int out_is_f32,
    float* __restrict__ sum, float* __restrict__ sumsq)
{
  const int N = 512;
  // unpadded [128][32] bf16 per buffer, chunk pos = kc ^ ((row>>1)&3)
  __shared__ u16 As[2][128 * 32];
  __shared__ u16 Bs[2][128 * 32];
  int tid  = threadIdx.x;
  int lane = tid & 63, wave = tid >> 6;   // 8 waves

  // swizzle decode: id%8 == bm%8 -> same-panel blocks share an XCD L2
  int id = blockIdx.x;
  int bm = (id & 7) + ((id >> 5) << 3);
  int bn = (id >> 3) & 3;

  int wm = (wave & 1) * 64, wn = (wave >> 1) * 32;   // 2x4 wave grid
  int r16 = lane & 15, quad = lane >> 4;

  floatx4 acc[4][2];
#pragma unroll
  for (int i = 0; i < 4; i++)
#pragma unroll
    for (int j = 0; j < 2; j++)
      acc[i][j] = (floatx4)(0.0f);

  const float* Ag = A  + (size_t)(bm * 128) * K;
  const u16*   Bg = BT + (size_t)(bn * 128) * K;

  // A staging: one row-chunk per thread (128 rows x 4 kc = 512 chunks)
  int ar  = tid >> 2;           // 0..127
  int akc = tid & 3;            // k-chunk (8 consecutive k)
  const float* ap = Ag + (size_t)ar * K + akc * 8;
  int adst = ar * 32 + ((akc ^ ((ar >> 1) & 3)) * 8);

  // B staging: one gld_lds16 per thread, linear LDS dest chunk p = tid,
  // pre-swizzled source: row = p>>2, pos = p&3, src kc = pos ^ ((row>>1)&3)
  int brow = tid >> 2, bpos = tid & 3;
  int bkc  = bpos ^ ((brow >> 1) & 3);
  const u16* bsrc = Bg + (size_t)brow * K + bkc * 8;
  int bdoff = tid * 8;          // elem offset: per wave = wave*1024 + lane*8 (16B/lane)

  int rsw = ((r16 >> 1) & 3) ^ quad;   // read chunk position (XOR un-swizzle)

  int NS = K >> 5;
  float4 a0, a1;

  // prologue: stage tile 0 into buffer 0
  a0 = *(const float4*)(ap);  a1 = *(const float4*)(ap + 4);
  gload_lds16(bsrc, &Bs[0][bdoff]);
  {
    uint4 tv;
    tv.x = cvtpk(a0.x, a0.y); tv.y = cvtpk(a0.z, a0.w);
    tv.z = cvtpk(a1.x, a1.y); tv.w = cvtpk(a1.z, a1.w);
    *(uint4*)(&As[0][adst]) = tv;
  }
  __syncthreads();

  int cur = 0;
  for (int ks = 0; ks < NS; ks++){
    int k1 = (ks + 1) << 5;
    if (ks + 1 < NS){
      // STAGE(k+1): issue loads early — latency hides under MFMA(k)
      a0 = *(const float4*)(ap + k1);  a1 = *(const float4*)(ap + k1 + 4);
      gload_lds16(bsrc + k1, &Bs[cur ^ 1][bdoff]);
    }
    short8 af[4], bfr[2];
#pragma unroll
    for (int i = 0; i < 4; i++) af[i]  = *(const short8*)(&As[cur][(wm + i*16 + r16) * 32 + rsw * 8]);
#pragma unroll
    for (int j = 0; j < 2; j++) bfr[j] = *(const short8*)(&Bs[cur][(wn + j*16 + r16) * 32 + rsw * 8]);
#pragma unroll
    for (int i = 0; i < 4; i++)
#pragma unroll
      for (int j = 0; j < 2; j++)
        acc[i][j] = __builtin_amdgcn_mfma_f32_16x16x32_bf16(af[i], bfr[j], acc[i][j], 0, 0, 0);
    if (ks + 1 < NS){
      uint4 tv;   // compiler waits vmcnt for a0/a1 here (B gld_lds stays in flight)
      tv.x = cvtpk(a0.x, a0.y); tv.y = cvtpk(a0.z, a0.w);
      tv.z = cvtpk(a1.x, a1.y); tv.w = cvtpk(a1.z, a1.w);
      *(uint4*)(&As[cur ^ 1][adst]) = tv;
    }
    __syncthreads();   // one barrier per K-step
    cur ^= 1;
  }

  // epilogue: C/D layout col = lane&15, row = quad*4 + reg (m89-verified)
  float cs[2] = {0.f, 0.f};
  float cq[2] = {0.f, 0.f};
#pragma unroll
  for (int i = 0; i < 4; i++){
    int rowb = bm * 128 + wm + i * 16 + quad * 4;
#pragma unroll
    for (int j = 0; j < 2; j++){
      int col = bn * 128 + wn + j * 16 + r16;
      float bv = bias[col];
#pragma unroll
      for (int r = 0; r < 4; r++){
        float v = acc[i][j][r] + bv;
        cs[j] += v; cq[j] += v * v;
        size_t idx = (size_t)(rowb + r) * N + col;
        if (out_is_f32) ((float*)Yv)[idx] = v;
        else            ((u16*)Yv)[idx]   = f2bf(v);
      }
    }
  }

  // column-stat reduction: quads within wave (shfl), wm-halves via LDS, 1 atomic each
#pragma unroll
  for (int j = 0; j < 2; j++){
    cs[j] += __shfl_xor(cs[j], 16); cs[j] += __shfl_xor(cs[j], 32);
    cq[j] += __shfl_xor(cq[j], 16); cq[j] += __shfl_xor(cq[j], 32);
  }
  float* S = (float*)As;   // reuse buffer: [wmh][stat][128 cols] = 512 f32
  if (lane < 16){
    int wmh = wave & 1;
#pragma unroll
    for (int j = 0; j < 2; j++){
      int c = wn + j * 16 + r16;            // each (wmh,c) written by exactly one wave
      S[wmh * 256 + c]       = cs[j];
      S[wmh * 256 + 128 + c] = cq[j];
    }
  }
  __syncthreads();
  if (tid < 256){
    int stat = tid >> 7, c = tid & 127;
    float v = S[stat * 128 + c] + S[256 + stat * 128 + c];
    float* dstp = stat ? sumsq : sum;
    atomicAdd(&dstp[bn * 128 + c], v);
  }
}

// ---- BN coefficients (block 0) + xyz2 passthrough copy (blocks 1..96) ----
__global__ void bn_coeff_copy(const float* __restrict__ stats,
                              const float* __restrict__ g1, const float* __restrict__ be1,
                              const float* __restrict__ g2, const float* __restrict__ be2,
                              float* __restrict__ coef,
                              const uint4* __restrict__ xsrc, uint4* __restrict__ xdst){
  int b = blockIdx.x, tid = threadIdx.x;
  if (b == 0){
    int c = tid;  // 512
    {
      float mu  = stats[c] / (float)M1;
      float var = stats[512 + c] / (float)M1 - mu * mu;
      var = fmaxf(var, 0.0f);
      float a = g1[c] * (1.0f / sqrtf(var + 1e-5f));
      coef[c] = a;
      coef[512 + c] = be1[c] - mu * a;
    }
    {
      float mu  = stats[1024 + c] / (float)M2;
      float var = stats[1536 + c] / (float)M2 - mu * mu;
      var = fmaxf(var, 0.0f);
      float a = g2[c] * (1.0f / sqrtf(var + 1e-5f));
      coef[1024 + c] = a;
      coef[1536 + c] = be2[c] - mu * a;
    }
  } else {
    int i = (b - 1) * 512 + tid;   // 96 * 512 = 49152 uint4 = 786432 B
    xdst[i] = xsrc[i];
  }
}

// ---- 3-NN inverse-distance interp FUSED with BN1/BN2+ReLU+add; one wave/query ----
// Fast path: f32 direct-form distances, key = (f32bits<<32)|idx. Accepted iff
// the rank-3/rank-4 gap exceeds (d3+d4)*2^-17 — f32 direct-form error is
// <= ~4eps*d ~ 2^-21*d, so an accepted top-3 SET provably equals the exact
// set; order within the set is irrelevant (weighted sum is symmetric).
// Guard is wave-uniform. Fallback (rare): exact-f64 masked-key path (round-3
// passing logic, verbatim).
__global__ __launch_bounds__(64) void interp_final(
    const float* __restrict__ xyz1, const float* __restrict__ xyz2,
    const u16* __restrict__ Y1, const float* __restrict__ coef,
    float* __restrict__ outF)
{
  int lane = threadIdx.x;
  int bid  = blockIdx.x;
  int b = bid >> 12;           // /4096

  const float* pd = xyz2 + (size_t)bid * 3;
  float xf = pd[0], yf = pd[1], zf = pd[2];
  const float* ps = xyz1 + (size_t)b * NN1 * 3;

  unsigned long long kl[16];
#pragma unroll
  for (int s = 0; s < 16; s++){
    const float* q = ps + (s * 64 + lane) * 3;
    float dx = xf - q[0], dy = yf - q[1], dz = zf - q[2];
    float d = fmaf(dx, dx, fmaf(dy, dy, dz * dz));
    kl[s] = ((unsigned long long)__float_as_uint(d) << 32)
          | (unsigned int)(s * 64 + lane);
  }

  unsigned long long selk[4];
#pragma unroll
  for (int p = 0; p < 4; p++){
    unsigned long long m = kl[0];
#pragma unroll
    for (int s = 1; s < 16; s++) if (kl[s] < m) m = kl[s];
    for (int off = 1; off < 64; off <<= 1){
      unsigned long long o = (unsigned long long)__shfl_xor((long long)m, off);
      if (o < m) m = o;
    }
    selk[p] = m;
    if (p < 3){
      // keys unique (idx embedded): exactly one (s,lane) matches
#pragma unroll
      for (int s = 0; s < 16; s++) if (kl[s] == m) kl[s] = ~0ULL;
    }
  }

  float d3 = __uint_as_float((unsigned int)(selk[2] >> 32));
  float d4 = __uint_as_float((unsigned int)(selk[3] >> 32));

  int i0, i1, i2;
  float f0, f1, f2;
  if (d4 - d3 > (d4 + d3) * 7.62939453125e-6f){   // 2^-17 margin, wave-uniform
    i0 = (int)(selk[0] & 0xFFFFFFFFULL);
    i1 = (int)(selk[1] & 0xFFFFFFFFULL);
    i2 = (int)(selk[2] & 0xFFFFFFFFULL);
    float e0 = __uint_as_float((unsigned int)(selk[0] >> 32));
    float e1 = __uint_as_float((unsigned int)(selk[1] >> 32));
    float w0 = rcpf(e0 + 1e-8f);
    float w1 = rcpf(e1 + 1e-8f);
    float w2 = rcpf(d3 + 1e-8f);
    float inv = rcpf(w0 + w1 + w2);
    f0 = w0 * inv; f1 = w1 * inv; f2 = w2 * inv;
  } else {
    // exact f64 fallback (round-3 passing logic)
    double xd = (double)xf, yd = (double)yf, zd = (double)zf;
#pragma unroll
    for (int s = 0; s < 16; s++){
      const float* q = ps + (s * 64 + lane) * 3;
      double dx = xd - (double)q[0];
      double dy = yd - (double)q[1];
      double dz = zd - (double)q[2];
      double d = dx * dx + dy * dy + dz * dz;
      unsigned long long bits = (unsigned long long)__double_as_longlong(d);
      kl[s] = (bits & ~1023ULL) | (unsigned long long)(s * 64 + lane);
    }
    unsigned long long sel2[3];
#pragma unroll
    for (int p = 0; p < 3; p++){
      unsigned long long m = kl[0];
#pragma unroll
      for (int s = 1; s < 16; s++) if (kl[s] < m) m = kl[s];
      for (int off = 1; off < 64; off <<= 1){
        unsigned long long o = (unsigned long long)__shfl_xor((long long)m, off);
        if (o < m) m = o;
      }
      sel2[p] = m;
      if (p < 2){
#pragma unroll
        for (int s = 0; s < 16; s++) if (kl[s] == m) kl[s] = ~0ULL;
      }
    }
    i0 = (int)(sel2[0] & 1023ULL);
    i1 = (int)(sel2[1] & 1023ULL);
    i2 = (int)(sel2[2] & 1023ULL);
    float e0 = (float)__longlong_as_double((long long)(sel2[0] & ~1023ULL));
    float e1 = (float)__longlong_as_double((long long)(sel2[1] & ~1023ULL));
    float e2 = (float)__longlong_as_double((long long)(sel2[2] & ~1023ULL));
    float w0 = rcpf(e0 + 1e-8f);
    float w1 = rcpf(e1 + 1e-8f);
    float w2 = rcpf(e2 + 1e-8f);
    float inv = rcpf(w0 + w1 + w2);
    f0 = w0 * inv; f1 = w1 * inv; f2 = w2 * inv;
  }

  const u16* r0 = Y1 + (size_t)(b * NN1 + i0) * DIM;
  const u16* r1 = Y1 + (size_t)(b * NN1 + i1) * DIM;
  const u16* r2 = Y1 + (size_t)(b * NN1 + i2) * DIM;
  float* o = outF + (size_t)bid * DIM;

  int c0 = lane * 8;  // 8 contiguous channels per lane
  uint4 q0 = *(const uint4*)(r0 + c0);
  uint4 q1 = *(const uint4*)(r1 + c0);
  uint4 q2 = *(const uint4*)(r2 + c0);
  float4 ylo = *(const float4*)(o + c0);
  float4 yhi = *(const float4*)(o + c0 + 4);
  union { float4 v[2]; float f[8]; } A1u, B1u, A2u, B2u;
  A1u.v[0] = *(const float4*)(coef + c0);        A1u.v[1] = *(const float4*)(coef + c0 + 4);
  B1u.v[0] = *(const float4*)(coef + 512 + c0);  B1u.v[1] = *(const float4*)(coef + 512 + c0 + 4);
  A2u.v[0] = *(const float4*)(coef + 1024 + c0); A2u.v[1] = *(const float4*)(coef + 1024 + c0 + 4);
  B2u.v[0] = *(const float4*)(coef + 1536 + c0); B2u.v[1] = *(const float4*)(coef + 1536 + c0 + 4);
  const u16* p0 = (const u16*)&q0;
  const u16* p1 = (const u16*)&q1;
  const u16* p2 = (const u16*)&q2;
  float yv[8] = { ylo.x, ylo.y, ylo.z, ylo.w, yhi.x, yhi.y, yhi.z, yhi.w };
  float res[8];
#pragma unroll
  for (int j = 0; j < 8; j++){
    float a1 = A1u.f[j], b1 = B1u.f[j];
    float a2 = A2u.f[j], b2 = B2u.f[j];
    float v0 = fmaxf(a1 * bf2f(p0[j]) + b1, 0.0f);
    float v1 = fmaxf(a1 * bf2f(p1[j]) + b1, 0.0f);
    float v2 = fmaxf(a1 * bf2f(p2[j]) + b1, 0.0f);
    float vi = f0 * v0 + f1 * v1 + f2 * v2;
    float y2 = fmaxf(a2 * yv[j] + b2, 0.0f);
    res[j] = vi + y2;
  }
  *(float4*)(o + c0)     = make_float4(res[0], res[1], res[2], res[3]);
  *(float4*)(o + c0 + 4) = make_float4(res[4], res[5], res[6], res[7]);
}

extern "C" void kernel_launch(void* const* d_in, const int* in_sizes, int n_in,
                              void* d_out, int out_size, void* d_ws, size_t ws_size,
                              hipStream_t stream){
  const float* xyz1    = (const float*)d_in[0];
  const float* points1 = (const float*)d_in[1];
  const float* xyz2    = (const float*)d_in[2];
  const float* points2 = (const float*)d_in[3];
  const float* fc1_w   = (const float*)d_in[4];
  const float* fc1_b   = (const float*)d_in[5];
  const float* bn1_g   = (const float*)d_in[6];
  const float* bn1_b   = (const float*)d_in[7];
  const float* fc2_w   = (const float*)d_in[8];
  const float* fc2_b   = (const float*)d_in[9];
  const float* bn2_g   = (const float*)d_in[10];
  const float* bn2_b   = (const float*)d_in[11];

  // workspace (~17.5 MB): Y1 bf16 + bf16 weight transposes + stats/coef
  char* ws = (char*)d_ws;
  u16*   Y1    = (u16*)(ws);                       // 16384*512*2 = 16,777,216 B
  u16*   wT1   = (u16*)(ws + 16777216);            // 512*1024*2 = 1,048,576 B
  u16*   wT2   = (u16*)(ws + 17825792);            // 512*512*2  =   524,288 B
  float* stats = (float*)(ws + 18350080);          // 2048 f32
  float* coef  = (float*)(ws + 18358272);          // 2048 f32

  float* out  = (float*)d_out;
  float* outF = out + 196608;   // feats region [65536][512] f32; holds pre-BN Y2 mid-flight

  prep<<<3072, 256, 0, stream>>>(fc1_w, fc2_w, wT1, wT2, stats);

  // 512-thread blocks; grid = (M/128)*4, swizzled (id%8 = XCD chunk)
  gemm_mfma<<<512, 512, 0, stream>>>(points1, wT1, fc1_b, Y1,   M1, 1024, 0,
                                     stats,        stats + 512);
  gemm_mfma<<<2048, 512, 0, stream>>>(points2, wT2, fc2_b, outF, M2,  512, 1,
                                      stats + 1024, stats + 1536);

  bn_coeff_copy<<<97, 512, 0, stream>>>(stats, bn1_g, bn1_b, bn2_g, bn2_b, coef,
                                        (const uint4*)xyz2, (uint4*)out);

  interp_final<<<65536, 64, 0, stream>>>(xyz1, xyz2, Y1, coef, outF);
}